// Round 2
// baseline (518.027 us; speedup 1.0000x reference)
//
#include <hip/hip_runtime.h>

#define HID 2048
#define NTHREADS 256   // 4 independent waves per block, one token per wave

typedef float f32x4 __attribute__((ext_vector_type(4)));

// One WAVE per token. Zero __syncthreads, zero LDS: the H=2048 reduction is
// a pure in-wave shfl_xor butterfly, so waves stream independently and the
// CU always has load-issuing waves available (fixes the 57% per-CU BW
// efficiency seen in R1 counters).
//
// Layouts (fp32): hs [4,T,HID], act [T,HID], rns [HID], rw [HID,4],
//                 pw [4,16], cw [4,4], cscale [HID], out [4,T,HID]
//
// Chunk c (0..7), lane l: float4 at c*256 + l*4  -> every load/store
// instruction covers 1 KB fully contiguous (full 64B lines).
__global__ __launch_bounds__(NTHREADS) void altup_fused(
    const float* __restrict__ hs,
    const float* __restrict__ act,
    const float* __restrict__ rns,
    const float* __restrict__ rw,
    const float* __restrict__ pw,
    const float* __restrict__ cw,
    const float* __restrict__ cscale,
    float* __restrict__ out,
    int T)
{
    const int wave = threadIdx.x >> 6;
    const int lane = threadIdx.x & 63;
    const int t    = blockIdx.x * 4 + wave;
    if (t >= T) return;

    const size_t tok     = (size_t)t * HID;
    const size_t strideN = (size_t)T * HID;
    const int    l4      = lane * 4;

    // ---- phase 1: 10 per-token reductions, accumulated over 8 chunks ----
    // x0/act are NOT kept in registers (reloaded from L2 in phase 2) to
    // stay <=~70 VGPR for 8 waves/SIMD.
    float red[10];
    #pragma unroll
    for (int k = 0; k < 10; ++k) red[k] = 0.f;

    #pragma unroll
    for (int c = 0; c < 8; ++c) {
        const int off = c * 256 + l4;
        float x0[4], a[4], ns[4], w[16];
        *(f32x4*)x0 = *(const f32x4*)(hs  + tok + off);
        *(f32x4*)a  = *(const f32x4*)(act + tok + off);
        *(f32x4*)ns = *(const f32x4*)(rns + off);
        #pragma unroll
        for (int r = 0; r < 4; ++r)
            *(f32x4*)(w + 4 * r) = *(const f32x4*)(rw + (size_t)(off + r) * 4);
        #pragma unroll
        for (int j = 0; j < 4; ++j) {
            float xv = x0[j], av = a[j], nv = ns[j];
            red[0] += xv * xv;
            red[1] += av * av;
            float xs = xv * nv, as_ = av * nv;
            #pragma unroll
            for (int n = 0; n < 4; ++n) {
                red[2 + n] += xs  * w[4 * j + n];
                red[6 + n] += as_ * w[4 * j + n];
            }
        }
    }

    // ---- in-wave butterfly: all 64 lanes end with the full sums ----
    #pragma unroll
    for (int m = 32; m > 0; m >>= 1) {
        #pragma unroll
        for (int k = 0; k < 10; ++k)
            red[k] += __shfl_xor(red[k], m, 64);
    }

    // ---- per-token scalars (redundant across lanes, trivially cheap) ----
    const float invH  = 1.0f / (float)HID;
    const float inv_p = rsqrtf(red[0] * invH + 1e-6f) * invH;
    const float inv_c = rsqrtf(red[1] * invH + 1e-6f) * invH;
    float mp[4], mc[4];
    #pragma unroll
    for (int n = 0; n < 4; ++n) {
        mp[n] = tanhf(red[2 + n] * inv_p);
        mc[n] = tanhf(red[6 + n] * inv_c);
    }
    float raw[16];
    #pragma unroll
    for (int kk = 0; kk < 16; ++kk)
        raw[kk] = mp[0] * pw[kk]      + mp[1] * pw[16 + kk]
                + mp[2] * pw[32 + kk] + mp[3] * pw[48 + kk];
    float coef[4];
    #pragma unroll
    for (int m = 0; m < 4; ++m)
        coef[m] = 1.0f + mc[0] * cw[m]     + mc[1] * cw[4 + m]
                       + mc[2] * cw[8 + m] + mc[3] * cw[12 + m];

    // ---- phase 2: pure streaming; x0/act reload hits L1/L2 ----
    #pragma unroll
    for (int c = 0; c < 8; ++c) {
        const int off = c * 256 + l4;
        float x0[4], x1[4], x2[4], x3[4], a[4], cs[4];
        *(f32x4*)x0 = *(const f32x4*)(hs + 0 * strideN + tok + off);
        *(f32x4*)x1 = *(const f32x4*)(hs + 1 * strideN + tok + off);
        *(f32x4*)x2 = *(const f32x4*)(hs + 2 * strideN + tok + off);
        *(f32x4*)x3 = *(const f32x4*)(hs + 3 * strideN + tok + off);
        *(f32x4*)a  = *(const f32x4*)(act + tok + off);
        *(f32x4*)cs = *(const f32x4*)(cscale + off);

        float o[4][4];
        #pragma unroll
        for (int j = 0; j < 4; ++j) {
            float x[4] = { x0[j], x1[j], x2[j], x3[j] };
            float pred[4];
            #pragma unroll
            for (int m = 0; m < 4; ++m)
                pred[m] = x[0] * raw[4 * m + 0] + x[1] * raw[4 * m + 1]
                        + x[2] * raw[4 * m + 2] + x[3] * raw[4 * m + 3] + x[m];
            float innov = a[j] - pred[0];
            #pragma unroll
            for (int m = 0; m < 4; ++m)
                o[m][j] = (pred[m] + innov * coef[m]) * cs[j];
        }
        #pragma unroll
        for (int m = 0; m < 4; ++m)
            __builtin_nontemporal_store(*(const f32x4*)o[m],
                (f32x4*)(out + (size_t)m * strideN + tok + off));
    }
}

extern "C" void kernel_launch(void* const* d_in, const int* in_sizes, int n_in,
                              void* d_out, int out_size, void* d_ws, size_t ws_size,
                              hipStream_t stream) {
    const float* hs  = (const float*)d_in[0]; // [4,B,S,H]
    const float* act = (const float*)d_in[1]; // [B,S,H]
    const float* rns = (const float*)d_in[2]; // [H]
    const float* rw  = (const float*)d_in[3]; // [H,4]
    const float* pw  = (const float*)d_in[4]; // [4,16]
    const float* cw  = (const float*)d_in[5]; // [4,4]
    const float* cs  = (const float*)d_in[6]; // [H]
    float* out = (float*)d_out;               // [4,B,S,H]

    const int T = in_sizes[1] / HID;  // B*S tokens
    altup_fused<<<dim3((T + 3) / 4), dim3(NTHREADS), 0, stream>>>(
        hs, act, rns, rw, pw, cw, cs, out, T);
}